// Round 13
// baseline (27.819 us; speedup 1.0000x reference)
//
#include <hip/hip_runtime.h>

#define HH 128
#define WW 192
#define HW (HH * WW)

typedef float f32x2v __attribute__((ext_vector_type(2)));
typedef __fp16 h2 __attribute__((ext_vector_type(2)));

__device__ __forceinline__ float relu(float v) { return fmaxf(v, 0.0f); }
__device__ __forceinline__ float fdot2(h2 a, h2 b, float c) {
    return __builtin_amdgcn_fdot2(a, b, c, false);
}
__device__ __forceinline__ h2 pkrtz(float a, float b) {
    return __builtin_amdgcn_cvt_pkrtz(a, b);
}

// LDS packed-weight layout (R11):
//   sWp (h2): [0..31] w0feat o*4+p=(w0[o][2+2p],w0[o][3+2p])
//             [32..63] w1 32+o*4+p=(w1[o][2p],w1[o][2p+1])
//             [64..67] w2 64+p=(w2[2p],w2[2p+1])
//   sF (f32): [0..7] w0x [8..15] w0y [16..23] b0 [24..31] b1 [32] b2

__global__ __launch_bounds__(256) void dmh_kernel(
    const float* __restrict__ mask_feats,   // (4,8,128,192)
    const float* __restrict__ params,       // (128,169)
    const float* __restrict__ locs,         // (128,2)
    const float* __restrict__ soi,          // (5,)
    const int*   __restrict__ im_inds,     // (128,)
    const int*   __restrict__ fpn_levels,  // (128,)
    const int*   __restrict__ stride_p,    // scalar (=8)
    float*       __restrict__ out)         // (128,1,256,384)
{
    const int tid  = threadIdx.x;
    const int lane = tid & 63;
    const int wid  = tid >> 6;
    const int g    = blockIdx.x * 4 + wid;  // row-group 0..63
    const int r    = 2 * g;                 // src rows r..r+2
    const int n    = blockIdx.y;            // instance

    __shared__ h2    sWp[68];
    __shared__ float sF[33];

    // ---- stage weights (fp16 packs for matmul, fp32 coords/biases) ----
    if (tid < 169) {
        float v = params[(size_t)n * 169 + tid];
        __fp16* sWh = reinterpret_cast<__fp16*>(sWp);
        if (tid < 80) {
            int o = tid / 10, k = tid - o * 10;
            if (k == 0)      sF[o] = v;
            else if (k == 1) sF[8 + o] = v;
            else { int f = k - 2; sWh[(o * 4 + (f >> 1)) * 2 + (f & 1)] = (__fp16)v; }
        } else if (tid < 144) {
            int t = tid - 80, o = t >> 3, i = t & 7;
            sWh[(32 + o * 4 + (i >> 1)) * 2 + (i & 1)] = (__fp16)v;
        } else if (tid < 152) {
            int o = tid - 144;
            sWh[(64 + (o >> 1)) * 2 + (o & 1)] = (__fp16)v;
        } else if (tid < 160) sF[16 + (tid - 152)] = v;
        else if (tid < 168)   sF[24 + (tid - 160)] = v;
        else                  sF[32] = v;
    }

    const int   stride = *stride_p;             // 8
    const float half_s = 0.5f * (float)stride;  // 4.0
    const float locx = locs[2 * n + 0];
    const float locy = locs[2 * n + 1];
    const float inv  = 1.0f / soi[fpn_levels[n]];
    const float* fb  = mask_feats + (size_t)im_inds[n] * 8 * HW;

    __syncthreads();
    // ---- from here: zero synchronization; every wave fully independent ----

    const int col0 = 3 * lane;                  // src cols col0..col0+2
    const float rxd = -(float)stride * inv;
    float rx0 = (locx - (float)(col0 * stride) - half_s) * inv;
    float rx1 = rx0 + rxd;
    float rx2 = rx1 + rxd;

    float L[3][3];                              // logits [rowi][col j]
    #pragma unroll
    for (int i = 0; i < 3; ++i) {
        const int srow = min(r + i, HH - 1);    // pad row replicates LOGITS -> clamp srow
        const float* fp = fb + srow * WW + col0;
        const float ry = (locy - (float)(srow * stride) - half_s) * inv;

        float x[8][3];
        #pragma unroll
        for (int ch = 0; ch < 8; ++ch) {
            x[ch][0] = fp[ch * HW + 0];
            x[ch][1] = fp[ch * HW + 1];
            x[ch][2] = fp[ch * HW + 2];
        }
        h2 xp[4][3];
        #pragma unroll
        for (int p = 0; p < 4; ++p)
            #pragma unroll
            for (int j = 0; j < 3; ++j)
                xp[p][j] = pkrtz(x[2 * p][j], x[2 * p + 1][j]);

        float h[8][3];
        #pragma unroll
        for (int o = 0; o < 8; ++o) {
            const h2 w0 = sWp[o * 4 + 0], w1 = sWp[o * 4 + 1],
                     w2 = sWp[o * 4 + 2], w3 = sWp[o * 4 + 3];
            float tO = fmaf(sF[8 + o], ry, sF[16 + o]);
            float wx = sF[o];
            float rxj[3] = {rx0, rx1, rx2};
            #pragma unroll
            for (int j = 0; j < 3; ++j) {
                float acc = fmaf(wx, rxj[j], tO);
                acc = fdot2(w0, xp[0][j], acc);
                acc = fdot2(w1, xp[1][j], acc);
                acc = fdot2(w2, xp[2][j], acc);
                acc = fdot2(w3, xp[3][j], acc);
                h[o][j] = acc;
            }
        }
        h2 hp[4][3];
        #pragma unroll
        for (int p = 0; p < 4; ++p)
            #pragma unroll
            for (int j = 0; j < 3; ++j)
                hp[p][j] = pkrtz(relu(h[2 * p][j]), relu(h[2 * p + 1][j]));

        float a[8][3];
        #pragma unroll
        for (int o = 0; o < 8; ++o) {
            const h2 w0 = sWp[32 + o * 4 + 0], w1 = sWp[32 + o * 4 + 1],
                     w2 = sWp[32 + o * 4 + 2], w3 = sWp[32 + o * 4 + 3];
            float b1 = sF[24 + o];
            #pragma unroll
            for (int j = 0; j < 3; ++j) {
                float acc = b1;
                acc = fdot2(w0, hp[0][j], acc);
                acc = fdot2(w1, hp[1][j], acc);
                acc = fdot2(w2, hp[2][j], acc);
                acc = fdot2(w3, hp[3][j], acc);
                a[o][j] = acc;
            }
        }
        const h2 v0 = sWp[64], v1 = sWp[65], v2 = sWp[66], v3 = sWp[67];
        const float b2v = sF[32];
        #pragma unroll
        for (int j = 0; j < 3; ++j) {
            h2 a0 = pkrtz(relu(a[0][j]), relu(a[1][j]));
            h2 a1 = pkrtz(relu(a[2][j]), relu(a[3][j]));
            h2 a2 = pkrtz(relu(a[4][j]), relu(a[5][j]));
            h2 a3 = pkrtz(relu(a[6][j]), relu(a[7][j]));
            float lg = b2v;
            lg = fdot2(v0, a0, lg);
            lg = fdot2(v1, a1, lg);
            lg = fdot2(v2, a2, lg);
            lg = fdot2(v3, a3, lg);
            L[i][j] = lg;
        }
    }

    // ---- col interp (align-corners x2 + edge pad): lane owns out cols 6c..6c+5 ----
    float ci[3][6];
    #pragma unroll
    for (int i = 0; i < 3; ++i) {
        float Lm1 = __shfl_up(L[i][2], 1);      // L(rowi, 3c-1) from lane-1
        if (lane == 0) Lm1 = L[i][0];           // col -1 pad -> col 0
        ci[i][0] = 0.5f * (Lm1 + L[i][0]);
        ci[i][1] = L[i][0];
        ci[i][2] = 0.5f * (L[i][0] + L[i][1]);
        ci[i][3] = L[i][1];
        ci[i][4] = 0.5f * (L[i][1] + L[i][2]);
        ci[i][5] = L[i][2];
    }

    // ---- row interp + stores: out rows 2r+1..2r+4 (+ row 0 for g==0) ----
    float* ob = out + (size_t)n * 256 * 384 + 6 * lane;
    auto store_row = [&](int y, const float* v) {
        float* p = ob + (size_t)y * 384;
        f32x2v s0 = {v[0], v[1]}, s1 = {v[2], v[3]}, s2 = {v[4], v[5]};
        *reinterpret_cast<f32x2v*>(p + 0) = s0;
        *reinterpret_cast<f32x2v*>(p + 2) = s1;
        *reinterpret_cast<f32x2v*>(p + 4) = s2;
    };
    float mid1[6], mid2[6];
    #pragma unroll
    for (int k = 0; k < 6; ++k) {
        mid1[k] = 0.5f * (ci[0][k] + ci[1][k]);
        mid2[k] = 0.5f * (ci[1][k] + ci[2][k]);
    }
    if (g == 0) store_row(0, ci[0]);            // out row 0 == row 1
    store_row(2 * r + 1, ci[0]);
    store_row(2 * r + 2, mid1);
    store_row(2 * r + 3, ci[1]);
    if (2 * r + 4 <= 255) store_row(2 * r + 4, mid2);
}

extern "C" void kernel_launch(void* const* d_in, const int* in_sizes, int n_in,
                              void* d_out, int out_size, void* d_ws, size_t ws_size,
                              hipStream_t stream) {
    const float* mask_feats = (const float*)d_in[0];
    const float* params     = (const float*)d_in[1];
    const float* locs       = (const float*)d_in[2];
    const float* soi        = (const float*)d_in[3];
    const int*   im_inds    = (const int*)d_in[4];
    const int*   fpn_levels = (const int*)d_in[5];
    const int*   stride_p   = (const int*)d_in[6];
    float* out = (float*)d_out;

    dim3 grid(16, 128);   // 16 blocks x 4 waves = 64 row-groups; 128 instances
    dim3 block(256);
    dmh_kernel<<<grid, block, 0, stream>>>(
        mask_feats, params, locs, soi, im_inds, fpn_levels, stride_p, out);
}